// Round 8
// baseline (121.772 us; speedup 1.0000x reference)
//
#include <hip/hip_runtime.h>
#include <math.h>

// VCDiscreteEstimator: B=65536, IN=128, OUT=257, NB=5 basis fns.
//   out[b,o] = sum_{i,n} z[b,i]*W[i,o,n]*basis[b,n] + sum_n bias[o,n]*basis[b,n]
//   prob[b]  = lerp(out[b,li], out[b,ui], dist), g=d*256, li=clip(floor(g),0,255)
// Only columns {li, ui=min(li+1,255)} are needed -> gather, don't GEMM.
// Bucket rows by cell: each block stages its cell's two weight columns (5 KB)
// in LDS once, reuses across ~256 rows. Weight traffic 336 MB -> ~10 MB;
// main kernel becomes z-HBM-bound (~32 MB).

constexpr int IN_F  = 128;
constexpr int OUTC  = 257;
constexpr int NB    = 5;
constexpr int CELLS = 256;
constexpr int CAP   = 1024;   // per-cell slot capacity (uniform d -> ~256/cell)
constexpr int SPLIT = 8;      // blocks per cell in main kernel

// d_ws layout (bytes):
//   [0,       1024)  cursor[256] (int)
//   [4096, 4096+1MB) order[CELLS*CAP] (int)
//   [WT_OFF, ...)    wT[OUTC][NB][IN_F] (float, 657,920 B)
constexpr size_t ORDER_OFF = 4096;
constexpr size_t WT_OFF    = ORDER_OFF + (size_t)CELLS * CAP * 4;   // 1,052,672
constexpr size_t WS_NEED   = WT_OFF + (size_t)OUTC * NB * IN_F * 4;

// ---------- K1: zero cursors + transpose W[i][o][n] -> wT[o][n][i] ----------
__global__ __launch_bounds__(256) void init_kernel(
    const float* __restrict__ w, float* __restrict__ wT, int* __restrict__ cursor)
{
    int idx = blockIdx.x * 256 + threadIdx.x;
    if (idx < CELLS) cursor[idx] = 0;
    constexpr int TOT = OUTC * NB * IN_F;
    if (idx < TOT) {
        int i    = idx & (IN_F - 1);
        int rest = idx >> 7;
        int n    = rest % NB;
        int o    = rest / NB;
        wT[idx] = w[(size_t)i * (OUTC * NB) + o * NB + n];
    }
}

// ---------- K2: bin rows by cell; overflow rows computed directly ----------
__global__ __launch_bounds__(256) void scatter_kernel(
    const float* __restrict__ dtr, const float* __restrict__ z,
    const float* __restrict__ wT,  const float* __restrict__ bias,
    int* __restrict__ cursor, int* __restrict__ order,
    float* __restrict__ out, int B)
{
    int row = blockIdx.x * 256 + threadIdx.x;
    if (row >= B) return;
    float dv = dtr[row];
    float g  = dv * 256.0f;
    int li   = (int)fminf(fmaxf(floorf(g), 0.0f), 255.0f);
    int slot = atomicAdd(&cursor[li], 1);
    if (slot < CAP) { order[li * CAP + slot] = row; return; }

    // Rare fallback (only if a cell exceeds CAP rows): compute this row here.
    int   ui   = min(li + 1, 255);
    float dist = g - (float)li;
    float b1 = dv, b2 = dv * dv;
    float r1 = fmaxf(dv - 0.33f, 0.0f), r2 = fmaxf(dv - 0.66f, 0.0f);
    float bas[NB] = {1.0f, b1, b2, r1 * r1, r2 * r2};
    const float* wl = wT + (size_t)li * (NB * IN_F);
    const float* wu = wT + (size_t)ui * (NB * IN_F);
    const float* zr = z + (size_t)row * IN_F;
    float accl = 0.0f, accu = 0.0f;
    for (int n = 0; n < NB; ++n) {
        float sl = 0.0f, su = 0.0f;
        for (int i = 0; i < IN_F; ++i) {
            sl = fmaf(zr[i], wl[n * IN_F + i], sl);
            su = fmaf(zr[i], wu[n * IN_F + i], su);
        }
        accl = fmaf(bas[n], sl, accl);
        accu = fmaf(bas[n], su, accu);
    }
    float bl = 0.0f, bu = 0.0f;
    for (int n = 0; n < NB; ++n) {
        bl = fmaf(bas[n], bias[li * NB + n], bl);
        bu = fmaf(bas[n], bias[ui * NB + n], bu);
    }
    float lb = accl + bl, ub = accu + bu;
    float prob = lb + (ub - lb) * dist;
    bool  sup  = (dv >= 0.0f) && (dv <= 1.0f);
    out[row] = sup ? prob : 0.0f;
}

// ---------- K3: per-cell main kernel, weight columns staged in LDS ----------
__global__ __launch_bounds__(256) void main_kernel(
    const float* __restrict__ dtr, const float* __restrict__ z,
    const float* __restrict__ wT,  const float* __restrict__ bias,
    const int* __restrict__ cursor, const int* __restrict__ order,
    float* __restrict__ out)
{
    __shared__ float lds[2 * NB * IN_F + 2 * NB + 6];   // 1296 floats
    int c = blockIdx.x / SPLIT;
    int s = blockIdx.x % SPLIT;
    int u = min(c + 1, 255);
    int tid = threadIdx.x;

    // stage: two contiguous 2560B columns of wT as float4 (320 float4 total,
    // strided so 256 threads cover all of them), plus the two bias rows.
    const float4* wl4 = reinterpret_cast<const float4*>(wT + (size_t)c * (NB * IN_F));
    const float4* wu4 = reinterpret_cast<const float4*>(wT + (size_t)u * (NB * IN_F));
    float4* l4 = reinterpret_cast<float4*>(lds);
    for (int k = tid; k < 320; k += 256)
        l4[k] = (k < 160) ? wl4[k] : wu4[k - 160];
    if (tid < NB)            lds[1280 + tid] = bias[c * NB + tid];
    else if (tid < 2 * NB)   lds[1280 + tid] = bias[u * NB + tid - NB];
    __syncthreads();

    int cnt  = min(cursor[c], CAP);
    int grp  = tid >> 4;     // 0..15 (4 groups per wave)
    int lane = tid & 15;

    for (int j = s * 16 + grp; j < cnt; j += SPLIT * 16) {
        int   row = order[c * CAP + j];
        float dv  = dtr[row];
        float b1 = dv, b2 = dv * dv;
        float r1 = fmaxf(dv - 0.33f, 0.0f), r2 = fmaxf(dv - 0.66f, 0.0f);
        float b3 = r1 * r1, b4 = r2 * r2;
        float dist = dv * 256.0f - (float)c;   // g - li (li == c by binning)

        const float4* zv = reinterpret_cast<const float4*>(z + (size_t)row * IN_F + lane * 8);
        float4 z0 = zv[0], z1 = zv[1];

        float accl = 0.0f, accu = 0.0f;
        #pragma unroll
        for (int n = 0; n < NB; ++n) {
            float bn = (n == 0) ? 1.0f : (n == 1) ? b1 : (n == 2) ? b2 : (n == 3) ? b3 : b4;
            const float4* ln4 = reinterpret_cast<const float4*>(lds + n * IN_F);
            const float4* un4 = reinterpret_cast<const float4*>(lds + NB * IN_F + n * IN_F);
            float4 l0 = ln4[lane * 2], l1 = ln4[lane * 2 + 1];
            float4 u0 = un4[lane * 2], u1 = un4[lane * 2 + 1];
            float dl = z0.x*l0.x + z0.y*l0.y + z0.z*l0.z + z0.w*l0.w
                     + z1.x*l1.x + z1.y*l1.y + z1.z*l1.z + z1.w*l1.w;
            float du = z0.x*u0.x + z0.y*u0.y + z0.z*u0.z + z0.w*u0.w
                     + z1.x*u1.x + z1.y*u1.y + z1.z*u1.z + z1.w*u1.w;
            accl = fmaf(bn, dl, accl);
            accu = fmaf(bn, du, accu);
        }

        // lerp before reduction (prob linear in accl/accu): 4 shuffles/row
        float comb = fmaf(dist, accu - accl, accl);
        #pragma unroll
        for (int m = 1; m < 16; m <<= 1)
            comb += __shfl_xor(comb, m, 64);

        if (lane == 0) {
            float bl = lds[1280] + b1*lds[1281] + b2*lds[1282] + b3*lds[1283] + b4*lds[1284];
            float bu = lds[1285] + b1*lds[1286] + b2*lds[1287] + b3*lds[1288] + b4*lds[1289];
            float prob = comb + fmaf(dist, bu - bl, bl);
            bool  sup  = (dv >= 0.0f) && (dv <= 1.0f);
            out[row] = sup ? prob : 0.0f;
        }
    }
}

// ---------- fallback (ws too small): direct gather, original layout ----------
__global__ __launch_bounds__(256) void direct_kernel(
    const float* __restrict__ dtr, const float* __restrict__ z,
    const float* __restrict__ w,   const float* __restrict__ bias,
    float* __restrict__ out, int B)
{
    int t   = blockIdx.x * blockDim.x + threadIdx.x;
    int row = t >> 4;
    int lane = threadIdx.x & 15;
    if (row >= B) return;
    float dv = dtr[row];
    float b1 = dv, b2 = dv * dv;
    float r1 = fmaxf(dv - 0.33f, 0.0f), r2 = fmaxf(dv - 0.66f, 0.0f);
    float b3 = r1 * r1, b4 = r2 * r2;
    float g = dv * 256.0f;
    float lower = fminf(fmaxf(floorf(g), 0.0f), 255.0f);
    float dist = g - lower;
    int li = (int)lower, ui = min(li + 1, 255);
    const float4* zv = reinterpret_cast<const float4*>(z + (size_t)row * IN_F + lane * 8);
    float4 z0 = zv[0], z1 = zv[1];
    float zz[8] = {z0.x, z0.y, z0.z, z0.w, z1.x, z1.y, z1.z, z1.w};
    float accl = 0.0f, accu = 0.0f;
    #pragma unroll
    for (int k = 0; k < 8; ++k) {
        const float* wp  = w + (size_t)(lane * 8 + k) * (OUTC * NB);
        const float* wlp = wp + li * NB;
        const float* wup = wp + ui * NB;
        float wsl = wlp[0] + b1*wlp[1] + b2*wlp[2] + b3*wlp[3] + b4*wlp[4];
        float wsu = wup[0] + b1*wup[1] + b2*wup[2] + b3*wup[3] + b4*wup[4];
        accl = fmaf(zz[k], wsl, accl);
        accu = fmaf(zz[k], wsu, accu);
    }
    float comb = fmaf(dist, accu - accl, accl);
    #pragma unroll
    for (int m = 1; m < 16; m <<= 1)
        comb += __shfl_xor(comb, m, 64);
    if (lane == 0) {
        const float* blp = bias + li * NB;
        const float* bup = bias + ui * NB;
        float bl = blp[0] + b1*blp[1] + b2*blp[2] + b3*blp[3] + b4*blp[4];
        float bu = bup[0] + b1*bup[1] + b2*bup[2] + b3*bup[3] + b4*bup[4];
        float prob = comb + fmaf(dist, bu - bl, bl);
        bool  sup  = (dv >= 0.0f) && (dv <= 1.0f);
        out[row] = sup ? prob : 0.0f;
    }
}

extern "C" void kernel_launch(void* const* d_in, const int* in_sizes, int n_in,
                              void* d_out, int out_size, void* d_ws, size_t ws_size,
                              hipStream_t stream) {
    const float* d_d = (const float*)d_in[0];   // d [B]
    const float* d_z = (const float*)d_in[1];   // z [B, 128]
    const float* d_w = (const float*)d_in[2];   // weight [128, 257, 5]
    const float* d_b = (const float*)d_in[3];   // bias [257, 5]
    float* out = (float*)d_out;
    int B = in_sizes[0];

    if (ws_size < WS_NEED) {
        direct_kernel<<<(B * 16 + 255) / 256, 256, 0, stream>>>(d_d, d_z, d_w, d_b, out, B);
        return;
    }

    int*   cursor = (int*)d_ws;
    int*   order  = (int*)((char*)d_ws + ORDER_OFF);
    float* wT     = (float*)((char*)d_ws + WT_OFF);

    constexpr int TOT = OUTC * NB * IN_F;
    init_kernel<<<(TOT + 255) / 256, 256, 0, stream>>>(d_w, wT, cursor);
    scatter_kernel<<<(B + 255) / 256, 256, 0, stream>>>(d_d, d_z, wT, d_b, cursor, order, out, B);
    main_kernel<<<CELLS * SPLIT, 256, 0, stream>>>(d_d, d_z, wT, d_b, cursor, order, out);
}

// Round 9
// 91.377 us; speedup vs baseline: 1.3326x; 1.3326x over previous
//
#include <hip/hip_runtime.h>
#include <math.h>

// VCDiscreteEstimator: B=65536, IN=128, OUT=257, NB=5.
// prob[b] = lerp(out[b,c], out[b,u], t),  c=clip(floor(256 d),0,255), u=min(c+1,255), t=256d-c
// out[b,o] = sum_i z[b,i]*P_{o,i}(d) + Pb_o(d), where P is quadratic in d per
// (column, i) once the relu kinks are resolved -> per-SUBCELL quadratic coeffs.
// Subcells: 256 cells + 2 extra (cell 84 split at 0.33, cell 168 split at 0.66).
// Table A[258][6][128]: for each subcell, {q0,q1,q2} x {lower,upper col} per i.
// Row kernel: 6 dot-products (3 KB table read/row, L2-resident 792 KB table),
// combine with Horner + lerp. No atomics, no LDS, 2 graph nodes.

constexpr int IN_F = 128;
constexpr int OUTC = 257;
constexpr int NSUB = 258;                       // 256 cells + 2 knot-split variants
constexpr size_t A_FLOATS  = (size_t)NSUB * 6 * IN_F;   // 198,144 floats
constexpr size_t BQ_OFF_F  = A_FLOATS;                  // Bq[258][6] appended
constexpr size_t WS_NEED   = (A_FLOATS + NSUB * 6) * sizeof(float);

// ---------- K1: per-subcell quadratic coefficients ----------
__global__ __launch_bounds__(256) void coeff_kernel(
    const float* __restrict__ w, const float* __restrict__ bias,
    float* __restrict__ A, float* __restrict__ Bq)
{
    int t = blockIdx.x * 256 + threadIdx.x;     // t = idx*128 + i
    if (t >= NSUB * IN_F) return;
    int i   = t & (IN_F - 1);
    int idx = t >> 7;
    int c   = (idx < 256) ? idx : (idx == 256 ? 84 : 168);
    int u   = min(c + 1, 255);
    // s1: relu(d-0.33) active on this subcell; s2 for 0.66.
    float s1 = ((c >= 85) || (idx == 256)) ? 1.0f : 0.0f;
    float s2 = ((c >= 169) || (idx == 257)) ? 1.0f : 0.0f;
    const float k1 = 0.33f, k2 = 0.66f;

    const float* wl = w + (size_t)i * (OUTC * 5) + c * 5;
    const float* wu = w + (size_t)i * (OUTC * 5) + u * 5;
    // P(d) = W0 + W1 d + W2 d^2 + s1(d-k1)^2 W3 + s2(d-k2)^2 W4  (expanded)
    float q0l = wl[0] + s1 * k1 * k1 * wl[3] + s2 * k2 * k2 * wl[4];
    float q1l = wl[1] - 2.0f * (s1 * k1 * wl[3] + s2 * k2 * wl[4]);
    float q2l = wl[2] + s1 * wl[3] + s2 * wl[4];
    float q0u = wu[0] + s1 * k1 * k1 * wu[3] + s2 * k2 * k2 * wu[4];
    float q1u = wu[1] - 2.0f * (s1 * k1 * wu[3] + s2 * k2 * wu[4]);
    float q2u = wu[2] + s1 * wu[3] + s2 * wu[4];

    float* Ai = A + (size_t)idx * (6 * IN_F);
    Ai[0 * IN_F + i] = q0l;  Ai[1 * IN_F + i] = q1l;  Ai[2 * IN_F + i] = q2l;
    Ai[3 * IN_F + i] = q0u;  Ai[4 * IN_F + i] = q1u;  Ai[5 * IN_F + i] = q2u;

    if (i == 0) {   // bias quadratics (one thread per subcell)
        const float* bl = bias + c * 5;
        const float* bu = bias + u * 5;
        float* bq = Bq + idx * 6;
        bq[0] = bl[0] + s1 * k1 * k1 * bl[3] + s2 * k2 * k2 * bl[4];
        bq[1] = bl[1] - 2.0f * (s1 * k1 * bl[3] + s2 * k2 * bl[4]);
        bq[2] = bl[2] + s1 * bl[3] + s2 * bl[4];
        bq[3] = bu[0] + s1 * k1 * k1 * bu[3] + s2 * k2 * k2 * bu[4];
        bq[4] = bu[1] - 2.0f * (s1 * k1 * bu[3] + s2 * k2 * bu[4]);
        bq[5] = bu[2] + s1 * bu[3] + s2 * bu[4];
    }
}

// ---------- K2: row evaluation. 16 lanes/row, 6 dots, Horner + lerp ----------
__global__ __launch_bounds__(256) void eval_kernel(
    const float* __restrict__ dtr, const float* __restrict__ z,
    const float* __restrict__ A,   const float* __restrict__ Bq,
    float* __restrict__ out, int B)
{
    int t   = blockIdx.x * 256 + threadIdx.x;
    int row = t >> 4;
    int s   = threadIdx.x & 15;
    if (row >= B) return;

    float dv = dtr[row];
    float g  = dv * 256.0f;
    float lower = fminf(fmaxf(floorf(g), 0.0f), 255.0f);
    int   c  = (int)lower;
    float x  = g - lower;                       // dist (t), in [0,1) for valid d
    int  idx = c;
    if      (c ==  84 && dv >= 0.33f) idx = 256;
    else if (c == 168 && dv >= 0.66f) idx = 257;

    const float4* zv = reinterpret_cast<const float4*>(z + (size_t)row * IN_F + s * 8);
    float4 z0 = zv[0], z1 = zv[1];

    const float* Ai = A + (size_t)idx * (6 * IN_F) + s * 8;
    float D[6];
    #pragma unroll
    for (int p = 0; p < 6; ++p) {
        const float4* ap = reinterpret_cast<const float4*>(Ai + p * IN_F);
        float4 a0 = ap[0], a1 = ap[1];
        D[p] = z0.x*a0.x + z0.y*a0.y + z0.z*a0.z + z0.w*a0.w
             + z1.x*a1.x + z1.y*a1.y + z1.z*a1.z + z1.w*a1.w;
    }
    // per-lane partial of Pl, Pu (quadratics in d), lerp before reduction
    float Pl = (D[2] * dv + D[1]) * dv + D[0];
    float Pu = (D[5] * dv + D[4]) * dv + D[3];
    float val = Pl + x * (Pu - Pl);

    #pragma unroll
    for (int m = 1; m < 16; m <<= 1)
        val += __shfl_xor(val, m, 64);

    if (s == 0) {
        const float* bq = Bq + idx * 6;
        float Bl = (bq[2] * dv + bq[1]) * dv + bq[0];
        float Bu = (bq[5] * dv + bq[4]) * dv + bq[3];
        val += Bl + x * (Bu - Bl);
        bool sup = (dv >= 0.0f) && (dv <= 1.0f);
        out[row] = sup ? val : 0.0f;
    }
}

// ---------- fallback (ws too small): direct gather from original layout ----------
__global__ __launch_bounds__(256) void direct_kernel(
    const float* __restrict__ dtr, const float* __restrict__ z,
    const float* __restrict__ w,   const float* __restrict__ bias,
    float* __restrict__ out, int B)
{
    int t   = blockIdx.x * blockDim.x + threadIdx.x;
    int row = t >> 4;
    int lane = threadIdx.x & 15;
    if (row >= B) return;
    float dv = dtr[row];
    float b1 = dv, b2 = dv * dv;
    float r1 = fmaxf(dv - 0.33f, 0.0f), r2 = fmaxf(dv - 0.66f, 0.0f);
    float b3 = r1 * r1, b4 = r2 * r2;
    float g = dv * 256.0f;
    float lower = fminf(fmaxf(floorf(g), 0.0f), 255.0f);
    float dist = g - lower;
    int li = (int)lower, ui = min(li + 1, 255);
    const float4* zv = reinterpret_cast<const float4*>(z + (size_t)row * IN_F + lane * 8);
    float4 z0 = zv[0], z1 = zv[1];
    float zz[8] = {z0.x, z0.y, z0.z, z0.w, z1.x, z1.y, z1.z, z1.w};
    float accl = 0.0f, accu = 0.0f;
    #pragma unroll
    for (int k = 0; k < 8; ++k) {
        const float* wp  = w + (size_t)(lane * 8 + k) * (OUTC * 5);
        const float* wlp = wp + li * 5;
        const float* wup = wp + ui * 5;
        float wsl = wlp[0] + b1*wlp[1] + b2*wlp[2] + b3*wlp[3] + b4*wlp[4];
        float wsu = wup[0] + b1*wup[1] + b2*wup[2] + b3*wup[3] + b4*wup[4];
        accl = fmaf(zz[k], wsl, accl);
        accu = fmaf(zz[k], wsu, accu);
    }
    float comb = fmaf(dist, accu - accl, accl);
    #pragma unroll
    for (int m = 1; m < 16; m <<= 1)
        comb += __shfl_xor(comb, m, 64);
    if (lane == 0) {
        const float* blp = bias + li * 5;
        const float* bup = bias + ui * 5;
        float bl = blp[0] + b1*blp[1] + b2*blp[2] + b3*blp[3] + b4*blp[4];
        float bu = bup[0] + b1*bup[1] + b2*bup[2] + b3*bup[3] + b4*bup[4];
        float prob = comb + fmaf(dist, bu - bl, bl);
        bool  sup  = (dv >= 0.0f) && (dv <= 1.0f);
        out[row] = sup ? prob : 0.0f;
    }
}

extern "C" void kernel_launch(void* const* d_in, const int* in_sizes, int n_in,
                              void* d_out, int out_size, void* d_ws, size_t ws_size,
                              hipStream_t stream) {
    const float* d_d = (const float*)d_in[0];   // d [B]
    const float* d_z = (const float*)d_in[1];   // z [B, 128]
    const float* d_w = (const float*)d_in[2];   // weight [128, 257, 5]
    const float* d_b = (const float*)d_in[3];   // bias [257, 5]
    float* out = (float*)d_out;
    int B = in_sizes[0];

    if (ws_size < WS_NEED) {
        direct_kernel<<<(B * 16 + 255) / 256, 256, 0, stream>>>(d_d, d_z, d_w, d_b, out, B);
        return;
    }

    float* A  = (float*)d_ws;
    float* Bq = (float*)d_ws + BQ_OFF_F;

    constexpr int CT = NSUB * IN_F;             // 33024 threads
    coeff_kernel<<<(CT + 255) / 256, 256, 0, stream>>>(d_w, d_b, A, Bq);
    eval_kernel<<<(B * 16 + 255) / 256, 256, 0, stream>>>(d_d, d_z, A, Bq, out, B);
}

// Round 10
// 87.659 us; speedup vs baseline: 1.3892x; 1.0424x over previous
//
#include <hip/hip_runtime.h>
#include <math.h>

// VCDiscreteEstimator: B=65536, IN=128, OUT=257, NB=5.
// prob[b] = lerp(out[b,c], out[b,u], x), c=clip(floor(256d),0,255), u=min(c+1,255), x=256d-c
// Only columns {c,u} are needed. On a SUBCELL (cell, resolved relu kinks),
// x is linear in d, so lerp(Pl(d),Pu(d),x) is a CUBIC in x per (subcell, i):
//   val = sum_i z_i * ((C3 x + C2) x + C1) x + C0)_i  + cubic bias
// Table C[258][4][128] (528 KB, L2-resident) + Cb[258][4].
// Subcells: 256 cells + 2 knot splits (0.33 in cell 84, 0.66 in cell 168).
// Expansion about cell start d0=c/256 keeps Horner in x within [0,1) --
// well-conditioned. 2 kernels, no atomics, no LDS.

constexpr int IN_F = 128;
constexpr int OUTC = 257;
constexpr int NSUB = 258;
constexpr size_t C_FLOATS = (size_t)NSUB * 4 * IN_F;   // 132,096 floats
constexpr size_t CB_OFF_F = C_FLOATS;                  // byte off 528384, 16B-aligned
constexpr size_t WS_NEED  = (C_FLOATS + NSUB * 4) * sizeof(float);

// ---------- K1: per-subcell cubic coefficients ----------
__global__ __launch_bounds__(256) void coeff_kernel(
    const float* __restrict__ w, const float* __restrict__ bias,
    float* __restrict__ C, float* __restrict__ Cb)
{
    int t = blockIdx.x * 256 + threadIdx.x;     // t = idx*128 + i
    if (t >= NSUB * IN_F) return;
    int i   = t & (IN_F - 1);
    int idx = t >> 7;
    int c   = (idx < 256) ? idx : (idx == 256 ? 84 : 168);
    int u   = min(c + 1, 255);
    float s1 = ((c >= 85)  || (idx == 256)) ? 1.0f : 0.0f;  // relu(d-0.33) active
    float s2 = ((c >= 169) || (idx == 257)) ? 1.0f : 0.0f;  // relu(d-0.66) active
    const float k1 = 0.33f, k2 = 0.66f, h = 1.0f / 256.0f;
    float d0 = (float)c * h;                    // expansion point (cell start)
    float e1 = d0 - k1, e2 = d0 - k2;

    // quadratic in x (d = d0 + h x) for one 5-coeff spline row:
    //   P(d) = W0 + W1 d + W2 d^2 + s1 W3 (d-k1)^2 + s2 W4 (d-k2)^2
    auto quad = [&](const float* __restrict__ W, float& p0, float& p1, float& p2) {
        p0 = W[0] + W[1] * d0 + W[2] * d0 * d0 + s1 * W[3] * e1 * e1 + s2 * W[4] * e2 * e2;
        p1 = h * (W[1] + 2.0f * (W[2] * d0 + s1 * W[3] * e1 + s2 * W[4] * e2));
        p2 = h * h * (W[2] + s1 * W[3] + s2 * W[4]);
    };

    const float* wl = w + (size_t)i * (OUTC * 5) + c * 5;
    const float* wu = w + (size_t)i * (OUTC * 5) + u * 5;
    float l0, l1, l2, u0, u1, u2;
    quad(wl, l0, l1, l2);
    quad(wu, u0, u1, u2);
    // val(x) = L(x) + x (U(x) - L(x))  -> cubic
    float* Ci = C + (size_t)idx * (4 * IN_F);
    Ci[0 * IN_F + i] = l0;
    Ci[1 * IN_F + i] = l1 + (u0 - l0);
    Ci[2 * IN_F + i] = l2 + (u1 - l1);
    Ci[3 * IN_F + i] = (u2 - l2);

    if (i == 0) {   // bias cubic (one thread per subcell)
        const float* bl = bias + c * 5;
        const float* bu = bias + u * 5;
        float a0, a1, a2, b0, b1, b2;
        quad(bl, a0, a1, a2);
        quad(bu, b0, b1, b2);
        float* cb = Cb + idx * 4;
        cb[0] = a0;
        cb[1] = a1 + (b0 - a0);
        cb[2] = a2 + (b1 - a1);
        cb[3] = (b2 - a2);
    }
}

// ---------- K2: row evaluation. 16 lanes/row, 4 dots, Horner in x ----------
__global__ __launch_bounds__(256) void eval_kernel(
    const float* __restrict__ dtr, const float* __restrict__ z,
    const float* __restrict__ C,   const float* __restrict__ Cb,
    float* __restrict__ out, int B)
{
    int t   = blockIdx.x * 256 + threadIdx.x;
    int row = t >> 4;
    int s   = threadIdx.x & 15;
    if (row >= B) return;

    float dv = dtr[row];
    float g  = dv * 256.0f;
    float lower = fminf(fmaxf(floorf(g), 0.0f), 255.0f);
    int   c  = (int)lower;
    float x  = g - lower;                       // in [0,1) for valid d
    int  idx = c;
    if      (c ==  84 && dv >= 0.33f) idx = 256;
    else if (c == 168 && dv >= 0.66f) idx = 257;

    const float4* zv = reinterpret_cast<const float4*>(z + (size_t)row * IN_F + s * 8);
    float4 z0 = zv[0], z1 = zv[1];

    const float* Ci = C + (size_t)idx * (4 * IN_F) + s * 8;
    float D[4];
    #pragma unroll
    for (int p = 0; p < 4; ++p) {
        const float4* cp = reinterpret_cast<const float4*>(Ci + p * IN_F);
        float4 a0 = cp[0], a1 = cp[1];
        D[p] = z0.x*a0.x + z0.y*a0.y + z0.z*a0.z + z0.w*a0.w
             + z1.x*a1.x + z1.y*a1.y + z1.z*a1.z + z1.w*a1.w;
    }
    float val = ((D[3] * x + D[2]) * x + D[1]) * x + D[0];

    #pragma unroll
    for (int m = 1; m < 16; m <<= 1)
        val += __shfl_xor(val, m, 64);

    if (s == 0) {
        float4 bq = *reinterpret_cast<const float4*>(Cb + idx * 4);
        val += ((bq.w * x + bq.z) * x + bq.y) * x + bq.x;
        bool sup = (dv >= 0.0f) && (dv <= 1.0f);
        out[row] = sup ? val : 0.0f;
    }
}

// ---------- fallback (ws too small): direct gather from original layout ----------
__global__ __launch_bounds__(256) void direct_kernel(
    const float* __restrict__ dtr, const float* __restrict__ z,
    const float* __restrict__ w,   const float* __restrict__ bias,
    float* __restrict__ out, int B)
{
    int t   = blockIdx.x * blockDim.x + threadIdx.x;
    int row = t >> 4;
    int lane = threadIdx.x & 15;
    if (row >= B) return;
    float dv = dtr[row];
    float b1 = dv, b2 = dv * dv;
    float r1 = fmaxf(dv - 0.33f, 0.0f), r2 = fmaxf(dv - 0.66f, 0.0f);
    float b3 = r1 * r1, b4 = r2 * r2;
    float g = dv * 256.0f;
    float lower = fminf(fmaxf(floorf(g), 0.0f), 255.0f);
    float dist = g - lower;
    int li = (int)lower, ui = min(li + 1, 255);
    const float4* zv = reinterpret_cast<const float4*>(z + (size_t)row * IN_F + lane * 8);
    float4 z0 = zv[0], z1 = zv[1];
    float zz[8] = {z0.x, z0.y, z0.z, z0.w, z1.x, z1.y, z1.z, z1.w};
    float accl = 0.0f, accu = 0.0f;
    #pragma unroll
    for (int k = 0; k < 8; ++k) {
        const float* wp  = w + (size_t)(lane * 8 + k) * (OUTC * 5);
        const float* wlp = wp + li * 5;
        const float* wup = wp + ui * 5;
        float wsl = wlp[0] + b1*wlp[1] + b2*wlp[2] + b3*wlp[3] + b4*wlp[4];
        float wsu = wup[0] + b1*wup[1] + b2*wup[2] + b3*wup[3] + b4*wup[4];
        accl = fmaf(zz[k], wsl, accl);
        accu = fmaf(zz[k], wsu, accu);
    }
    float comb = fmaf(dist, accu - accl, accl);
    #pragma unroll
    for (int m = 1; m < 16; m <<= 1)
        comb += __shfl_xor(comb, m, 64);
    if (lane == 0) {
        const float* blp = bias + li * 5;
        const float* bup = bias + ui * 5;
        float bl = blp[0] + b1*blp[1] + b2*blp[2] + b3*blp[3] + b4*blp[4];
        float bu = bup[0] + b1*bup[1] + b2*bup[2] + b3*bup[3] + b4*bup[4];
        float prob = comb + fmaf(dist, bu - bl, bl);
        bool  sup  = (dv >= 0.0f) && (dv <= 1.0f);
        out[row] = sup ? prob : 0.0f;
    }
}

extern "C" void kernel_launch(void* const* d_in, const int* in_sizes, int n_in,
                              void* d_out, int out_size, void* d_ws, size_t ws_size,
                              hipStream_t stream) {
    const float* d_d = (const float*)d_in[0];   // d [B]
    const float* d_z = (const float*)d_in[1];   // z [B, 128]
    const float* d_w = (const float*)d_in[2];   // weight [128, 257, 5]
    const float* d_b = (const float*)d_in[3];   // bias [257, 5]
    float* out = (float*)d_out;
    int B = in_sizes[0];

    if (ws_size < WS_NEED) {
        direct_kernel<<<(B * 16 + 255) / 256, 256, 0, stream>>>(d_d, d_z, d_w, d_b, out, B);
        return;
    }

    float* C  = (float*)d_ws;
    float* Cb = (float*)d_ws + CB_OFF_F;

    constexpr int CT = NSUB * IN_F;             // 33024 threads
    coeff_kernel<<<(CT + 255) / 256, 256, 0, stream>>>(d_w, d_b, C, Cb);
    eval_kernel<<<(B * 16 + 255) / 256, 256, 0, stream>>>(d_d, d_z, C, Cb, out, B);
}